// Round 1
// baseline (623.680 us; speedup 1.0000x reference)
//
#include <hip/hip_runtime.h>
#include <math.h>

// Problem constants
#define B_    256
#define N_    35
#define I_    64
#define H_    256
#define ROWS  8960            // B_*N_
#define ELEMS 2293760L        // ROWS*H_

typedef __bf16 bf16x8 __attribute__((ext_vector_type(8)));
typedef float f32x4 __attribute__((ext_vector_type(4)));

struct XPtrs { const float* p[12]; };
struct HPtrs { const float* p[7]; };
struct GB    { const __bf16* a0[12]; const __bf16* a1[12]; const float* hp[12]; };
struct MshA  { const __bf16* oa[4]; const __bf16* ob[4]; const __bf16* oc[4];
               const float* S[4]; __bf16* com; float* accs; };

#define GLOAD_LDS16(g, l) __builtin_amdgcn_global_load_lds( \
    (const __attribute__((address_space(1))) unsigned int*)(g), \
    (__attribute__((address_space(3))) unsigned int*)(l), 16, 0, 0)

// ---------------- prep: zero accs (blk 28) + compose adjacencies (blk 0..23) + L1 (blk 24..27) ----
__global__ void prep_kernel(const float* __restrict__ As_, const float* __restrict__ Af_,
                            const float* __restrict__ At_, float* __restrict__ A12,
                            float* __restrict__ A12sq,
                            const float* __restrict__ S0, const float* __restrict__ S1,
                            const float* __restrict__ S2, const float* __restrict__ S3,
                            float* __restrict__ l1out, float* __restrict__ accs) {
    int blk = blockIdx.x;
    if (blk >= 28) {
        if (threadIdx.x < 8) accs[threadIdx.x] = 0.f;
        return;
    }
    if (blk >= 24) {
        const float* mats[4] = {S0, S1, S2, S3};
        const float* S = mats[blk - 24];
        float s = 0.f;
        for (int i = threadIdx.x; i < N_ * N_; i += 256) s += fabsf(S[i]);
        for (int off = 32; off > 0; off >>= 1) s += __shfl_down(s, off);
        __shared__ float wr[4];
        if ((threadIdx.x & 63) == 0) wr[threadIdx.x >> 6] = s;
        __syncthreads();
        if (threadIdx.x == 0) l1out[blk - 24] = wr[0] + wr[1] + wr[2] + wr[3];
        return;
    }
    int v = blk / 12, r = blk % 12;
    __shared__ float M[3][N_ * N_];
    for (int i = threadIdx.x; i < N_ * N_; i += blockDim.x) {
        float a = As_[i], f = Af_[i], t = At_[i];
        if (v) { a *= a; f *= f; t *= t; }
        M[0][i] = a; M[1][i] = f; M[2][i] = t;
    }
    __syncthreads();
    const int kind[12] = {0,0,0, 1,1,1,1,1,1, 2,2,2};
    const int ia[12]   = {0,1,2, 0,1,0,2,1,2, 0,0,2};
    const int ib[12]   = {0,1,2, 1,0,2,0,2,1, 1,2,0};
    const int ic[12]   = {0,0,0, 0,0,0,0,0,0, 2,1,1};
    const float* Ma = M[ia[r]];
    const float* Mb = M[ib[r]];
    const float* Mc = M[ic[r]];
    float* dst = (v ? A12sq : A12) + r * N_ * N_;
    for (int i = threadIdx.x; i < N_ * N_; i += blockDim.x) {
        int m = i / N_, n = i % N_;
        float acc;
        if (kind[r] == 0) {
            acc = Ma[i];
        } else if (kind[r] == 1) {
            acc = 0.f;
            for (int p = 0; p < N_; p++) acc += Ma[m*N_+p] * Mb[p*N_+n];
        } else {
            acc = 0.f;
            for (int p = 0; p < N_; p++) {
                float t = 0.f;
                for (int q = 0; q < N_; q++) t += Mb[p*N_+q] * Mc[q*N_+n];
                acc += Ma[m*N_+p] * t;
            }
        }
        dst[i] = acc;
    }
}

// ---------------- basis-composed weights, transposed to [r][o][k] bf16 ----------------
__global__ void wc_kernel(const float* __restrict__ V1, const float* __restrict__ c1,
                          const float* __restrict__ V2, const float* __restrict__ c2,
                          __bf16* __restrict__ WcT) {
    int idx = blockIdx.x * 256 + threadIdx.x;   // 12*256*128
    int k = idx & 127;
    int o = (idx >> 7) & 255;
    int r = idx >> 15;
    float acc = 0.f;
    if (k < 64) {
        for (int bb = 0; bb < 4; bb++) acc += c1[r*4+bb] * V1[((long)bb*64 + k)*256 + o];
    } else {
        int kk = k - 64;
        for (int bb = 0; bb < 4; bb++) acc += c2[r*4+bb] * V2[((long)bb*64 + kk)*256 + o];
    }
    WcT[idx] = (__bf16)acc;
}

// ---------------- GRU weight transpose: [7][512k][256n] fp32 -> [mat][g][256n][512k] bf16 ----------------
__global__ void wt_kernel(const float* __restrict__ Wr, const float* __restrict__ Wz,
                          const float* __restrict__ Wh, __bf16* __restrict__ WT) {
    int z = blockIdx.z;              // 0..20
    int mat = z / 7, g = z % 7;
    const float* srcs[3] = {Wr, Wz, Wh};
    const float* src = srcs[mat] + (long)g * 512 * 256;
    __bf16* dst = WT + ((long)mat * 7 + g) * 256 * 512;
    int n0 = blockIdx.x * 64;        // grid.x = 4
    int k0 = blockIdx.y * 64;        // grid.y = 8
    __shared__ float T[64][65];
    int c = threadIdx.x & 63, r0 = threadIdx.x >> 6;
    for (int r = r0; r < 64; r += 4)
        T[r][c] = src[(long)(k0 + r) * 256 + n0 + c];
    __syncthreads();
    for (int n = r0; n < 64; n += 4)
        dst[(long)(n0 + n) * 512 + k0 + c] = (__bf16)T[c][n];
}

// ---------------- hidden fp32 -> bf16 cast ----------------
__global__ void hcast_kernel(HPtrs hp, __bf16* __restrict__ out) {
    int g = blockIdx.y;
    long idx = ((long)blockIdx.x * 256 + threadIdx.x) * 4;   // grid.x = 2240
    float4 v = *(const float4*)(hp.p[g] + idx);
    __bf16* o = out + (long)g * ELEMS + idx;
    o[0] = (__bf16)v.x; o[1] = (__bf16)v.y; o[2] = (__bf16)v.z; o[3] = (__bf16)v.w;
}

// ---------------- xA fold: register-cached x, scalar(SGPR) A, pure v_fmac loop ----------------
__global__ __launch_bounds__(256)
void xa_kernel(XPtrs xp, const float* __restrict__ A12, const float* __restrict__ A12sq,
               __bf16* __restrict__ xAc) {
    int r = blockIdx.x;
    int w = __builtin_amdgcn_readfirstlane(threadIdx.x >> 6);
    int v = w & 1, bl = w >> 1;
    int lane = threadIdx.x & 63;
    int b = blockIdx.y * 2 + bl;
    const float* x = xp.p[r] + (long)b * (N_ * I_);
    const float* As = (v ? A12sq : A12) + r * (N_ * N_);
    float xv[N_];
#pragma unroll
    for (int n = 0; n < N_; n++) xv[n] = x[n * I_ + lane];
    float acc[N_];
#pragma unroll
    for (int m = 0; m < N_; m++) acc[m] = 0.f;
#pragma unroll
    for (int n = 0; n < N_; n++) {
#pragma unroll
        for (int m = 0; m < N_; m++) acc[m] += As[m * N_ + n] * xv[n];
    }
    long obase = ((long)r * ROWS + (long)b * N_) * 128 + v * 64 + lane;
#pragma unroll
    for (int m = 0; m < N_; m++) xAc[obase + (long)m * 128] = (__bf16)acc[m];
}

// ---------------- bf16 MFMA GEMM, 128x128 tile, 4 waves x 64x64 ----------
// v2: double-buffered LDS + 1-step prefetch; conflict-free chunked LDS layout
//     ([kq][16row][8elem] per 16x32 chunk, produced by permuting the global
//     source lane mapping — LDS dest stays linear as global_load_lds requires).
// A row-major bf16; k-split at K0 between a0[bz] (lda0) / a1[bz] (lda1).
// B is B^T row-major [N][K] bf16, n-split at N0 between B0/B1 (same ldb), z-stride bstr.
// ACT: 3 GRU-final (fp32 out; Zb bf16 z at [row*512+256+col], hp fp32 h)
//      4 split-relu sum (bf16 out)
//      5 gru-gates (bf16 out: col<256 -> sigmoid*h, col>=256 -> sigmoid)
template<int ACT>
__global__ __launch_bounds__(256)
void gemm_bf16(GB gb, int K0, int K, int lda0, int lda1,
               const __bf16* __restrict__ B0, const __bf16* __restrict__ B1,
               int N0, int ldb, long bstr,
               void* __restrict__ Cp, int ldc, long cstr,
               const __bf16* __restrict__ Zb, long zstr) {
    int bz = blockIdx.z;
    int n0 = blockIdx.x * 128;
    int m0 = blockIdx.y * 128;
    const __bf16* a0 = gb.a0[bz];
    const __bf16* a1 = gb.a1[bz];
    const __bf16* bbase = ((n0 < N0) ? B0 : B1) + bz * bstr;
    int nloc = (n0 < N0) ? n0 : (n0 - N0);
    __shared__ __bf16 As[2][8 * 512];   // 2 x 8KB
    __shared__ __bf16 Bs[2][8 * 512];   // 2 x 8KB
    int tid = threadIdx.x;
    int lane = tid & 63;
    int w = tid >> 6;
    int wm = (w & 1) * 64, wn = (w >> 1) * 64;
    int l15 = lane & 15, q = lane >> 4;
    int kq8 = q * 8;                 // source k-offset for staging (elements)
    int ca = (w & 1) * 4;            // A chunk base for this wave's frag reads
    int cb = (w >> 1) * 4;           // B chunk base
    f32x4 acc[4][4] = {};
    f32x4 accA[4][4];   // only live for ACT==4
    int ksplit = K >> 1;

    // Stage one 32-wide K-step into LDS buffer `buf`.
    // Lane l of wave w loads row (base + (l&15)), k-slot (l>>4); linear LDS dest
    // l*16B then realizes chunk layout [kq][16row][16B] -> conflict-free ds_read_b128.
    auto stage = [&](int buf, int kt2) {
        const __bf16* aseg; int kk; int lda;
        if (kt2 < K0) { aseg = a0; kk = kt2; lda = lda0; }
        else          { aseg = a1; kk = kt2 - K0; lda = lda1; }
        GLOAD_LDS16(aseg + (long)(m0 + w * 16 + l15) * lda + kk + kq8,      &As[buf][w * 512]);
        GLOAD_LDS16(aseg + (long)(m0 + 64 + w * 16 + l15) * lda + kk + kq8, &As[buf][(4 + w) * 512]);
        GLOAD_LDS16(bbase + (long)(nloc + w * 16 + l15) * ldb + kt2 + kq8,      &Bs[buf][w * 512]);
        GLOAD_LDS16(bbase + (long)(nloc + 64 + w * 16 + l15) * ldb + kt2 + kq8, &Bs[buf][(4 + w) * 512]);
    };

    stage(0, 0);
    int cur = 0;
    for (int kt = 0; kt < K; kt += 32) {
        __syncthreads();                       // drains vmcnt(0): stage(kt) landed; prev reads done
        if (kt + 32 < K) stage(cur ^ 1, kt + 32);   // prefetch hides under ds_read+MFMA below
        const __bf16* Ac = As[cur];
        const __bf16* Bc = Bs[cur];
        bf16x8 af[4], bfr[4];
#pragma unroll
        for (int mt = 0; mt < 4; mt++) af[mt]  = *(const bf16x8*)(Ac + (ca + mt) * 512 + q * 128 + l15 * 8);
#pragma unroll
        for (int nt = 0; nt < 4; nt++) bfr[nt] = *(const bf16x8*)(Bc + (cb + nt) * 512 + q * 128 + l15 * 8);
#pragma unroll
        for (int mt = 0; mt < 4; mt++)
#pragma unroll
            for (int nt = 0; nt < 4; nt++)
                acc[mt][nt] = __builtin_amdgcn_mfma_f32_16x16x32_bf16(af[mt], bfr[nt], acc[mt][nt], 0, 0, 0);
        if (ACT == 4 && (kt + 32) == ksplit) {
#pragma unroll
            for (int mt = 0; mt < 4; mt++)
#pragma unroll
                for (int nt = 0; nt < 4; nt++)
#pragma unroll
                    for (int r = 0; r < 4; r++) {
                        accA[mt][nt][r] = fmaxf(acc[mt][nt][r], 0.f);
                        acc[mt][nt][r] = 0.f;
                    }
        }
        cur ^= 1;
    }

#pragma unroll
    for (int mt = 0; mt < 4; mt++) {
#pragma unroll
        for (int nt = 0; nt < 4; nt++) {
#pragma unroll
            for (int r = 0; r < 4; r++) {
                long row = m0 + wm + mt*16 + q*4 + r;
                int col  = n0 + wn + nt*16 + l15;
                float vv = acc[mt][nt][r];
                if (ACT == 3) {
                    float zz = (float)Zb[bz*zstr + row * 512 + 256 + col];
                    float hv = gb.hp[bz][row * 256 + col];
                    // fast tanh: 1 - 2/(e^{2x}+1)
                    float e = __expf(2.f * vv);
                    float th = 1.f - 2.f * __builtin_amdgcn_rcpf(e + 1.f);
                    ((float*)Cp)[bz*cstr + row * ldc + col] = (1.f - zz) * hv + zz * th;
                } else if (ACT == 5) {
                    float s = __builtin_amdgcn_rcpf(1.f + __expf(-vv));
                    if (col < 256) s *= gb.hp[bz][row * 256 + col];
                    ((__bf16*)Cp)[bz*cstr + row * ldc + col] = (__bf16)s;
                } else {  // ACT 4
                    ((__bf16*)Cp)[bz*cstr + row * ldc + col] = (__bf16)(accA[mt][nt][r] + fmaxf(vv, 0.f));
                }
            }
        }
    }
}

// ---------------- msh + sim + com: register-cached o, scalar S, pure v_fmac ----------------
// grid (256 b, 4 h-tile, 4 z); wave w handles nodes mm = w, w+4, ...
__global__ __launch_bounds__(256, 1)
void msh_kernel(MshA ma) {
    int z = blockIdx.z;
    bool tri = (z == 3);
    int b = blockIdx.x;
    int h0 = blockIdx.y * 64;
    int lane = threadIdx.x & 63;
    int w = __builtin_amdgcn_readfirstlane(threadIdx.x >> 6);
    long base = (long)b * N_ * H_ + h0 + lane;
    const __bf16* pa = ma.oa[z] + base;
    const __bf16* pb = ma.ob[z] + base;
    const __bf16* pc = ma.oc[z] + base;
    float av[N_], bv[N_], cv[N_];
#pragma unroll
    for (int n = 0; n < N_; n++) {
        av[n] = (float)pa[n * H_];
        bv[n] = (float)pb[n * H_];
    }
    if (tri) {
#pragma unroll
        for (int n = 0; n < N_; n++) cv[n] = (float)pc[n * H_];
    }
    const float* S = ma.S[z];
    __bf16* com = ma.com + (long)z * ELEMS + base;
    float lsum = 0.f;
    for (int mm = w; mm < N_; mm += 4) {        // mm wave-uniform
        float a = 0.f, bb = 0.f, cc = 0.f;
#pragma unroll
        for (int n = 0; n < N_; n++) {
            float s = S[n * N_ + mm];           // uniform -> s_load
            a += av[n] * s;
            bb += bv[n] * s;
            if (tri) cc += cv[n] * s;
        }
        if (tri) {
            com[(long)mm * H_] = (__bf16)((a + bb + cc) * (1.f/3.f));
            float d1 = a - bb, d2 = a - cc, d3 = bb - cc;
            lsum += d1*d1 + d2*d2 + d3*d3;
        } else {
            com[(long)mm * H_] = (__bf16)(0.5f * (a + bb));
            float d = a - bb;
            lsum += d * d;
        }
    }
    for (int off = 32; off > 0; off >>= 1) lsum += __shfl_down(lsum, off);
    __shared__ float wred[4];
    if (lane == 0) wred[w] = lsum;
    __syncthreads();
    if (threadIdx.x == 0) atomicAdd(ma.accs + z, wred[0] + wred[1] + wred[2] + wred[3]);
}

// ---------------- finalize sims ----------------
__global__ void fin_kernel(const float* __restrict__ accs, float* __restrict__ outp) {
    if (threadIdx.x == 0) {
        float inv = 1.f / 2293760.f;
        outp[0] = accs[0] * inv;
        outp[1] = accs[1] * inv;
        outp[2] = accs[2] * inv;
        outp[3] = accs[3] * inv;
    }
}

extern "C" void kernel_launch(void* const* d_in, const int* in_sizes, int n_in,
                              void* d_out, int out_size, void* d_ws, size_t ws_size,
                              hipStream_t stream) {
    const float* const* in = (const float* const*)d_in;
    float* out = (float*)d_out;
    char* ws = (char*)d_ws;

    size_t off = 0;
    auto alloc = [&](size_t bytes) { size_t o = off; off += (bytes + 255) & ~(size_t)255; return o; };
    float*  A12   = (float*)(ws + alloc(12*N_*N_*4));
    float*  A12sq = (float*)(ws + alloc(12*N_*N_*4));
    __bf16* WcT   = (__bf16*)(ws + alloc((size_t)12*256*128*2));
    __bf16* WT    = (__bf16*)(ws + alloc((size_t)21*256*512*2));
    float*  accs  = (float*)(ws + alloc(256));
    __bf16* gout  = (__bf16*)(ws + alloc((size_t)12*ELEMS*2));
    __bf16* com   = (__bf16*)(ws + alloc((size_t)4*ELEMS*2));
    __bf16* hbf   = (__bf16*)(ws + alloc((size_t)7*ELEMS*2));
    size_t  tail  = alloc((size_t)7*ROWS*512*2);      // rhz region (64.2 MB)
    __bf16* rhz   = (__bf16*)(ws + tail);
    __bf16* xAc   = (__bf16*)(ws + tail);             // aliases rhz; dead before gates GEMM

    XPtrs xp;
    for (int i = 0; i < 12; i++) xp.p[i] = in[i];
    HPtrs hp;
    for (int i = 0; i < 7; i++) hp.p[i] = in[15 + i];

    prep_kernel<<<29, 256, 0, stream>>>(in[12], in[13], in[14], A12, A12sq,
                                        in[27], in[26], in[28], in[29],
                                        out + 7L*ELEMS + 4, accs);
    wc_kernel<<<(12*128*256)/256, 256, 0, stream>>>(in[22], in[23], in[24], in[25], WcT);
    wt_kernel<<<dim3(4, 8, 21), 256, 0, stream>>>(in[30], in[31], in[32], WT);
    hcast_kernel<<<dim3(2240, 7), 256, 0, stream>>>(hp, hbf);
    xa_kernel<<<dim3(12, 128), 256, 0, stream>>>(xp, A12, A12sq, xAc);

    // GCN: gout[r] = relu(xA1@W1) + relu(xA2@W2)  (ACT=4 split-relu at K/2=64)
    {
        GB gb{};
        for (int z = 0; z < 12; z++) { gb.a0[z] = xAc + (long)z*ROWS*128; gb.a1[z] = gb.a0[z]; }
        gemm_bf16<4><<<dim3(2, 70, 12), 256, 0, stream>>>(
            gb, 128, 128, 128, 128,
            WcT, WcT, 256, 128, 32768L,
            gout, 256, ELEMS, (const __bf16*)nullptr, 0L);
    }

    // msh + sim + com (4 batched in z)
    {
        MshA ma{};
        ma.oa[0] = gout + 3L*ELEMS; ma.ob[0] = gout + 4L*ELEMS; ma.oc[0] = ma.oa[0];
        ma.oa[1] = gout + 5L*ELEMS; ma.ob[1] = gout + 6L*ELEMS; ma.oc[1] = ma.oa[1];
        ma.oa[2] = gout + 7L*ELEMS; ma.ob[2] = gout + 8L*ELEMS; ma.oc[2] = ma.oa[2];
        ma.oa[3] = gout + 9L*ELEMS; ma.ob[3] = gout + 10L*ELEMS; ma.oc[3] = gout + 11L*ELEMS;
        ma.S[0] = in[26]; ma.S[1] = in[27]; ma.S[2] = in[28]; ma.S[3] = in[29];
        ma.com = com; ma.accs = accs;
        msh_kernel<<<dim3(256, 4, 4), 256, 0, stream>>>(ma);
    }

    fin_kernel<<<1, 64, 0, stream>>>(accs, out + 7L*ELEMS);

    // GRU gates, batched over g: rhz[g] = [sig(x1@Wr)*h | sig(x1@Wz)]  (bf16)
    {
        GB gb{};
        for (int g = 0; g < 7; g++) {
            gb.a0[g] = (g < 3) ? gout + (long)g*ELEMS : com + (long)(g - 3)*ELEMS;
            gb.a1[g] = hbf + (long)g*ELEMS;
            gb.hp[g] = in[15 + g];
        }
        gemm_bf16<5><<<dim3(4, 70, 7), 256, 0, stream>>>(
            gb, 256, 512, 256, 256,
            WT, WT + 7L*131072, 256, 512, 131072L,
            rhz, 512, (long)ROWS*512, (const __bf16*)nullptr, 0L);
    }

    // GRU final, batched: out[g] = (1-z)*h + z*tanh([rh|o]@Wh)  (fp32 to d_out)
    {
        GB gb{};
        for (int g = 0; g < 7; g++) {
            gb.a0[g] = rhz + (long)g*ROWS*512;
            gb.a1[g] = (g < 3) ? gout + (long)g*ELEMS : com + (long)(g - 3)*ELEMS;
            gb.hp[g] = in[15 + g];
        }
        gemm_bf16<3><<<dim3(2, 70, 7), 256, 0, stream>>>(
            gb, 256, 512, 512, 256,
            WT + 14L*131072, WT + 14L*131072, 256, 512, 131072L,
            out, 256, ELEMS, rhz, (long)ROWS*512);
    }
}

// Round 2
// 569.517 us; speedup vs baseline: 1.0951x; 1.0951x over previous
//
#include <hip/hip_runtime.h>
#include <math.h>

// Problem constants
#define B_    256
#define N_    35
#define I_    64
#define H_    256
#define ROWS  8960            // B_*N_
#define ELEMS 2293760L        // ROWS*H_

typedef __bf16 bf16x8 __attribute__((ext_vector_type(8)));
typedef float f32x4 __attribute__((ext_vector_type(4)));

struct XPtrs { const float* p[12]; };
struct HPtrs { const float* p[7]; };
struct GB    { const __bf16* a0[12]; const __bf16* a1[12]; const float* hp[12]; };
struct MshA  { const __bf16* oa[4]; const __bf16* ob[4]; const __bf16* oc[4];
               const float* S[4]; __bf16* com; float* accs; };

#define GLOAD_LDS16(g, l) __builtin_amdgcn_global_load_lds( \
    (const __attribute__((address_space(1))) unsigned int*)(g), \
    (__attribute__((address_space(3))) unsigned int*)(l), 16, 0, 0)

// ---------------- prep: zero accs (blk 28) + compose adjacencies (blk 0..23) + L1 (blk 24..27) ----
__global__ void prep_kernel(const float* __restrict__ As_, const float* __restrict__ Af_,
                            const float* __restrict__ At_, float* __restrict__ A12,
                            float* __restrict__ A12sq,
                            const float* __restrict__ S0, const float* __restrict__ S1,
                            const float* __restrict__ S2, const float* __restrict__ S3,
                            float* __restrict__ l1out, float* __restrict__ accs) {
    int blk = blockIdx.x;
    if (blk >= 28) {
        if (threadIdx.x < 8) accs[threadIdx.x] = 0.f;
        return;
    }
    if (blk >= 24) {
        const float* mats[4] = {S0, S1, S2, S3};
        const float* S = mats[blk - 24];
        float s = 0.f;
        for (int i = threadIdx.x; i < N_ * N_; i += 256) s += fabsf(S[i]);
        for (int off = 32; off > 0; off >>= 1) s += __shfl_down(s, off);
        __shared__ float wr[4];
        if ((threadIdx.x & 63) == 0) wr[threadIdx.x >> 6] = s;
        __syncthreads();
        if (threadIdx.x == 0) l1out[blk - 24] = wr[0] + wr[1] + wr[2] + wr[3];
        return;
    }
    int v = blk / 12, r = blk % 12;
    __shared__ float M[3][N_ * N_];
    for (int i = threadIdx.x; i < N_ * N_; i += blockDim.x) {
        float a = As_[i], f = Af_[i], t = At_[i];
        if (v) { a *= a; f *= f; t *= t; }
        M[0][i] = a; M[1][i] = f; M[2][i] = t;
    }
    __syncthreads();
    const int kind[12] = {0,0,0, 1,1,1,1,1,1, 2,2,2};
    const int ia[12]   = {0,1,2, 0,1,0,2,1,2, 0,0,2};
    const int ib[12]   = {0,1,2, 1,0,2,0,2,1, 1,2,0};
    const int ic[12]   = {0,0,0, 0,0,0,0,0,0, 2,1,1};
    const float* Ma = M[ia[r]];
    const float* Mb = M[ib[r]];
    const float* Mc = M[ic[r]];
    float* dst = (v ? A12sq : A12) + r * N_ * N_;
    for (int i = threadIdx.x; i < N_ * N_; i += blockDim.x) {
        int m = i / N_, n = i % N_;
        float acc;
        if (kind[r] == 0) {
            acc = Ma[i];
        } else if (kind[r] == 1) {
            acc = 0.f;
            for (int p = 0; p < N_; p++) acc += Ma[m*N_+p] * Mb[p*N_+n];
        } else {
            acc = 0.f;
            for (int p = 0; p < N_; p++) {
                float t = 0.f;
                for (int q = 0; q < N_; q++) t += Mb[p*N_+q] * Mc[q*N_+n];
                acc += Ma[m*N_+p] * t;
            }
        }
        dst[i] = acc;
    }
}

// ---------------- basis-composed weights, transposed to [r][o][k] bf16 ----------------
__global__ void wc_kernel(const float* __restrict__ V1, const float* __restrict__ c1,
                          const float* __restrict__ V2, const float* __restrict__ c2,
                          __bf16* __restrict__ WcT) {
    int idx = blockIdx.x * 256 + threadIdx.x;   // 12*256*128
    int k = idx & 127;
    int o = (idx >> 7) & 255;
    int r = idx >> 15;
    float acc = 0.f;
    if (k < 64) {
        for (int bb = 0; bb < 4; bb++) acc += c1[r*4+bb] * V1[((long)bb*64 + k)*256 + o];
    } else {
        int kk = k - 64;
        for (int bb = 0; bb < 4; bb++) acc += c2[r*4+bb] * V2[((long)bb*64 + kk)*256 + o];
    }
    WcT[idx] = (__bf16)acc;
}

// ---------------- GRU weight transpose: [7][512k][256n] fp32 -> [mat][g][256n][512k] bf16 ----------------
__global__ void wt_kernel(const float* __restrict__ Wr, const float* __restrict__ Wz,
                          const float* __restrict__ Wh, __bf16* __restrict__ WT) {
    int z = blockIdx.z;              // 0..20
    int mat = z / 7, g = z % 7;
    const float* srcs[3] = {Wr, Wz, Wh};
    const float* src = srcs[mat] + (long)g * 512 * 256;
    __bf16* dst = WT + ((long)mat * 7 + g) * 256 * 512;
    int n0 = blockIdx.x * 64;        // grid.x = 4
    int k0 = blockIdx.y * 64;        // grid.y = 8
    __shared__ float T[64][65];
    int c = threadIdx.x & 63, r0 = threadIdx.x >> 6;
    for (int r = r0; r < 64; r += 4)
        T[r][c] = src[(long)(k0 + r) * 256 + n0 + c];
    __syncthreads();
    for (int n = r0; n < 64; n += 4)
        dst[(long)(n0 + n) * 512 + k0 + c] = (__bf16)T[c][n];
}

// ---------------- hidden fp32 -> bf16 cast ----------------
__global__ void hcast_kernel(HPtrs hp, __bf16* __restrict__ out) {
    int g = blockIdx.y;
    long idx = ((long)blockIdx.x * 256 + threadIdx.x) * 4;   // grid.x = 2240
    float4 v = *(const float4*)(hp.p[g] + idx);
    __bf16* o = out + (long)g * ELEMS + idx;
    o[0] = (__bf16)v.x; o[1] = (__bf16)v.y; o[2] = (__bf16)v.z; o[3] = (__bf16)v.w;
}

// ---------------- xA fold: register-cached x, scalar(SGPR) A, pure v_fmac loop ----------------
__global__ __launch_bounds__(256)
void xa_kernel(XPtrs xp, const float* __restrict__ A12, const float* __restrict__ A12sq,
               __bf16* __restrict__ xAc) {
    int r = blockIdx.x;
    int w = __builtin_amdgcn_readfirstlane(threadIdx.x >> 6);
    int v = w & 1, bl = w >> 1;
    int lane = threadIdx.x & 63;
    int b = blockIdx.y * 2 + bl;
    const float* x = xp.p[r] + (long)b * (N_ * I_);
    const float* As = (v ? A12sq : A12) + r * (N_ * N_);
    float xv[N_];
#pragma unroll
    for (int n = 0; n < N_; n++) xv[n] = x[n * I_ + lane];
    float acc[N_];
#pragma unroll
    for (int m = 0; m < N_; m++) acc[m] = 0.f;
#pragma unroll
    for (int n = 0; n < N_; n++) {
#pragma unroll
        for (int m = 0; m < N_; m++) acc[m] += As[m * N_ + n] * xv[n];
    }
    long obase = ((long)r * ROWS + (long)b * N_) * 128 + v * 64 + lane;
#pragma unroll
    for (int m = 0; m < N_; m++) xAc[obase + (long)m * 128] = (__bf16)acc[m];
}

// ---------------- bf16 MFMA GEMM (GCN only now), 128x128 tile, conflict-free chunked LDS ----
template<int ACT>
__global__ __launch_bounds__(256)
void gemm_bf16(GB gb, int K0, int K, int lda0, int lda1,
               const __bf16* __restrict__ B0, const __bf16* __restrict__ B1,
               int N0, int ldb, long bstr,
               void* __restrict__ Cp, int ldc, long cstr,
               const __bf16* __restrict__ Zb, long zstr) {
    int bz = blockIdx.z;
    int n0 = blockIdx.x * 128;
    int m0 = blockIdx.y * 128;
    const __bf16* a0 = gb.a0[bz];
    const __bf16* a1 = gb.a1[bz];
    const __bf16* bbase = ((n0 < N0) ? B0 : B1) + bz * bstr;
    int nloc = (n0 < N0) ? n0 : (n0 - N0);
    __shared__ __bf16 As[2][8 * 512];   // 2 x 8KB
    __shared__ __bf16 Bs[2][8 * 512];   // 2 x 8KB
    int tid = threadIdx.x;
    int lane = tid & 63;
    int w = tid >> 6;
    int wm = (w & 1) * 64, wn = (w >> 1) * 64;
    int l15 = lane & 15, q = lane >> 4;
    int kq8 = q * 8;                 // source k-offset for staging (elements)
    int ca = (w & 1) * 4;            // A chunk base for this wave's frag reads
    int cb = (w >> 1) * 4;           // B chunk base
    f32x4 acc[4][4] = {};
    f32x4 accA[4][4];   // only live for ACT==4
    int ksplit = K >> 1;

    auto stage = [&](int buf, int kt2) {
        const __bf16* aseg; int kk; int lda;
        if (kt2 < K0) { aseg = a0; kk = kt2; lda = lda0; }
        else          { aseg = a1; kk = kt2 - K0; lda = lda1; }
        GLOAD_LDS16(aseg + (long)(m0 + w * 16 + l15) * lda + kk + kq8,      &As[buf][w * 512]);
        GLOAD_LDS16(aseg + (long)(m0 + 64 + w * 16 + l15) * lda + kk + kq8, &As[buf][(4 + w) * 512]);
        GLOAD_LDS16(bbase + (long)(nloc + w * 16 + l15) * ldb + kt2 + kq8,      &Bs[buf][w * 512]);
        GLOAD_LDS16(bbase + (long)(nloc + 64 + w * 16 + l15) * ldb + kt2 + kq8, &Bs[buf][(4 + w) * 512]);
    };

    stage(0, 0);
    int cur = 0;
    for (int kt = 0; kt < K; kt += 32) {
        __syncthreads();
        if (kt + 32 < K) stage(cur ^ 1, kt + 32);
        const __bf16* Ac = As[cur];
        const __bf16* Bc = Bs[cur];
        bf16x8 af[4], bfr[4];
#pragma unroll
        for (int mt = 0; mt < 4; mt++) af[mt]  = *(const bf16x8*)(Ac + (ca + mt) * 512 + q * 128 + l15 * 8);
#pragma unroll
        for (int nt = 0; nt < 4; nt++) bfr[nt] = *(const bf16x8*)(Bc + (cb + nt) * 512 + q * 128 + l15 * 8);
#pragma unroll
        for (int mt = 0; mt < 4; mt++)
#pragma unroll
            for (int nt = 0; nt < 4; nt++)
                acc[mt][nt] = __builtin_amdgcn_mfma_f32_16x16x32_bf16(af[mt], bfr[nt], acc[mt][nt], 0, 0, 0);
        if (ACT == 4 && (kt + 32) == ksplit) {
#pragma unroll
            for (int mt = 0; mt < 4; mt++)
#pragma unroll
                for (int nt = 0; nt < 4; nt++)
#pragma unroll
                    for (int r = 0; r < 4; r++) {
                        accA[mt][nt][r] = fmaxf(acc[mt][nt][r], 0.f);
                        acc[mt][nt][r] = 0.f;
                    }
        }
        cur ^= 1;
    }

#pragma unroll
    for (int mt = 0; mt < 4; mt++) {
#pragma unroll
        for (int nt = 0; nt < 4; nt++) {
#pragma unroll
            for (int r = 0; r < 4; r++) {
                long row = m0 + wm + mt*16 + q*4 + r;
                int col  = n0 + wn + nt*16 + l15;
                float vv = acc[mt][nt][r];
                ((__bf16*)Cp)[bz*cstr + row * ldc + col] = (__bf16)(accA[mt][nt][r] + fmaxf(vv, 0.f));
            }
        }
    }
}

// ---------------- fused GRU: gates GEMM + rh/z build + final GEMM + GRU epilogue ----------
// Per block: 32 rows x full width, one g. K-loops barrier-free (B direct-to-register,
// A resident in LDS chunked layout). 2 barriers total.
// LDS map (bf16 elems): A1c [0,16384) 32KB, RH [16384,24576) 16KB, ZB [24576,32768) 16KB.
#define RHB 16384
#define ZBB 24576
__global__ __launch_bounds__(256, 2)
void gru_fused(GB gb, const __bf16* __restrict__ WT, float* __restrict__ outp) {
    __shared__ __bf16 sm[32768];     // 64KB
    int g = blockIdx.y;
    int m0 = blockIdx.x * 32;
    int tid = threadIdx.x;
    int lane = tid & 63;
    int w = tid >> 6;
    int l15 = lane & 15, q = lane >> 4;
    const float* hpg = gb.hp[g];

    // ---- stage A1 = [o | h] (32 rows x 512 k) into chunked LDS ----
    // chunk c = ck*2 + cr (ck: 32-k group, cr: 16-row group); wave w: c = w*8 .. w*8+7.
    // waves 0,1 read a0 (o part, k<256), waves 2,3 read a1 (h part).
    {
        const __bf16* src = (w < 2) ? gb.a0[g] : gb.a1[g];
#pragma unroll
        for (int i = 0; i < 8; i++) {
            int c = w * 8 + i;
            int ck = c >> 1, cr = c & 1;
            GLOAD_LDS16(src + (long)(m0 + cr * 16 + l15) * 256 + (ck & 7) * 32 + q * 8,
                        &sm[c * 512]);
        }
    }

    // ---- phase 1: gates = A1 @ [Wr|Wz]  (M=32, N=512, K=512) ----
    // wave w covers gate cols w*128..w*128+128 (w<2 -> r via Wr, w>=2 -> z via Wz)
    const __bf16* wrz = WT + ((w < 2) ? (long)g * 131072 : (long)(7 + g) * 131072);
    const __bf16* b1base = wrz + (long)((w & 1) * 128 + l15) * 512 + q * 8;
    auto loadB1 = [&](bf16x8* d, int s) {
#pragma unroll
        for (int nt = 0; nt < 8; nt++)
            d[nt] = *(const bf16x8*)(b1base + nt * 8192 + s * 32);
    };
    auto afrag1 = [&](bf16x8* d, int s) {
#pragma unroll
        for (int mt = 0; mt < 2; mt++)
            d[mt] = *(const bf16x8*)(&sm[(s * 2 + mt) * 512 + q * 128 + l15 * 8]);
    };

    bf16x8 bA[8], bB[8];
    loadB1(bA, 0);
    loadB1(bB, 1);
    __syncthreads();                 // A1c resident (drains all vmem incl. bA,bB)

    f32x4 acc[2][8] = {};
#pragma unroll
    for (int s = 0; s < 16; s += 2) {
        bf16x8 af[2];
        afrag1(af, s);
#pragma unroll
        for (int mt = 0; mt < 2; mt++)
#pragma unroll
            for (int nt = 0; nt < 8; nt++)
                acc[mt][nt] = __builtin_amdgcn_mfma_f32_16x16x32_bf16(af[mt], bA[nt], acc[mt][nt], 0, 0, 0);
        if (s + 2 < 16) loadB1(bA, s + 2);
        afrag1(af, s + 1);
#pragma unroll
        for (int mt = 0; mt < 2; mt++)
#pragma unroll
            for (int nt = 0; nt < 8; nt++)
                acc[mt][nt] = __builtin_amdgcn_mfma_f32_16x16x32_bf16(af[mt], bB[nt], acc[mt][nt], 0, 0, 0);
        if (s + 3 < 16) loadB1(bB, s + 3);
    }

    // ---- phase-1 epilogue: waves 0,1 -> RH = sigmoid(r)*h(fp32); waves 2,3 -> ZB = sigmoid(z) ----
    if (w < 2) {
#pragma unroll
        for (int mt = 0; mt < 2; mt++)
#pragma unroll
            for (int nt = 0; nt < 8; nt++)
#pragma unroll
                for (int j = 0; j < 4; j++) {
                    int row = mt * 16 + q * 4 + j;
                    int colg = w * 128 + nt * 16 + l15;
                    float rv = __builtin_amdgcn_rcpf(1.f + __expf(-acc[mt][nt][j]));
                    float hb = hpg[(long)(m0 + row) * 256 + colg];
                    int rhoff = RHB + ((w * 4 + (nt >> 1)) * 2 + mt) * 512
                              + ((nt * 2 + (l15 >> 3)) & 3) * 128 + (q * 4 + j) * 8 + (l15 & 7);
                    sm[rhoff] = (__bf16)(rv * hb);
                }
    } else {
#pragma unroll
        for (int mt = 0; mt < 2; mt++)
#pragma unroll
            for (int nt = 0; nt < 8; nt++)
#pragma unroll
                for (int j = 0; j < 4; j++) {
                    int row = mt * 16 + q * 4 + j;
                    int colp = (w - 2) * 128 + nt * 16 + l15;
                    float zv = __builtin_amdgcn_rcpf(1.f + __expf(-acc[mt][nt][j]));
                    sm[ZBB + row * 256 + colp] = (__bf16)zv;
                }
    }

    // ---- phase 2: hh = [rh | o] @ Wh  (M=32, N=256, K=512); wave w -> out cols w*64.. ----
    const __bf16* wh = WT + (long)(14 + g) * 131072;
    const __bf16* b2base = wh + (long)(w * 64 + l15) * 512 + q * 8;
    auto loadB2 = [&](bf16x8* d, int s) {
#pragma unroll
        for (int nt = 0; nt < 4; nt++)
            d[nt] = *(const bf16x8*)(b2base + nt * 8192 + s * 32);
    };
    auto afrag2 = [&](bf16x8* d, int s) {
#pragma unroll
        for (int mt = 0; mt < 2; mt++) {
            int off = (s < 8) ? (RHB + (s * 2 + mt) * 512) : (((s - 8) * 2 + mt) * 512);
            d[mt] = *(const bf16x8*)(&sm[off + q * 128 + l15 * 8]);
        }
    };

    bf16x8 cA[4], cB[4];
    loadB2(cA, 0);
    loadB2(cB, 1);
    __syncthreads();                 // RH/ZB writes visible (drains cA,cB too)

    f32x4 acc2[2][4] = {};
#pragma unroll
    for (int s = 0; s < 16; s += 2) {
        bf16x8 af[2];
        afrag2(af, s);
#pragma unroll
        for (int mt = 0; mt < 2; mt++)
#pragma unroll
            for (int nt = 0; nt < 4; nt++)
                acc2[mt][nt] = __builtin_amdgcn_mfma_f32_16x16x32_bf16(af[mt], cA[nt], acc2[mt][nt], 0, 0, 0);
        if (s + 2 < 16) loadB2(cA, s + 2);
        afrag2(af, s + 1);
#pragma unroll
        for (int mt = 0; mt < 2; mt++)
#pragma unroll
            for (int nt = 0; nt < 4; nt++)
                acc2[mt][nt] = __builtin_amdgcn_mfma_f32_16x16x32_bf16(af[mt], cB[nt], acc2[mt][nt], 0, 0, 0);
        if (s + 3 < 16) loadB2(cB, s + 3);
    }

    // ---- GRU epilogue: out = (1-z)*h + z*tanh(hh) ----
    float* og = outp + (long)g * ELEMS;
#pragma unroll
    for (int mt = 0; mt < 2; mt++)
#pragma unroll
        for (int nt = 0; nt < 4; nt++)
#pragma unroll
            for (int j = 0; j < 4; j++) {
                int row = mt * 16 + q * 4 + j;
                int col = w * 64 + nt * 16 + l15;
                float zz = (float)sm[ZBB + row * 256 + col];
                float e = __expf(2.f * acc2[mt][nt][j]);
                float th = 1.f - 2.f * __builtin_amdgcn_rcpf(e + 1.f);
                float hv = hpg[(long)(m0 + row) * 256 + col];
                og[(long)(m0 + row) * 256 + col] = (1.f - zz) * hv + zz * th;
            }
}

// ---------------- msh + sim + com: register-cached o, scalar S, pure v_fmac ----------------
__global__ __launch_bounds__(256, 1)
void msh_kernel(MshA ma) {
    int z = blockIdx.z;
    bool tri = (z == 3);
    int b = blockIdx.x;
    int h0 = blockIdx.y * 64;
    int lane = threadIdx.x & 63;
    int w = __builtin_amdgcn_readfirstlane(threadIdx.x >> 6);
    long base = (long)b * N_ * H_ + h0 + lane;
    const __bf16* pa = ma.oa[z] + base;
    const __bf16* pb = ma.ob[z] + base;
    const __bf16* pc = ma.oc[z] + base;
    float av[N_], bv[N_], cv[N_];
#pragma unroll
    for (int n = 0; n < N_; n++) {
        av[n] = (float)pa[n * H_];
        bv[n] = (float)pb[n * H_];
    }
    if (tri) {
#pragma unroll
        for (int n = 0; n < N_; n++) cv[n] = (float)pc[n * H_];
    }
    const float* S = ma.S[z];
    __bf16* com = ma.com + (long)z * ELEMS + base;
    float lsum = 0.f;
    for (int mm = w; mm < N_; mm += 4) {        // mm wave-uniform
        float a = 0.f, bb = 0.f, cc = 0.f;
#pragma unroll
        for (int n = 0; n < N_; n++) {
            float s = S[n * N_ + mm];           // uniform -> s_load
            a += av[n] * s;
            bb += bv[n] * s;
            if (tri) cc += cv[n] * s;
        }
        if (tri) {
            com[(long)mm * H_] = (__bf16)((a + bb + cc) * (1.f/3.f));
            float d1 = a - bb, d2 = a - cc, d3 = bb - cc;
            lsum += d1*d1 + d2*d2 + d3*d3;
        } else {
            com[(long)mm * H_] = (__bf16)(0.5f * (a + bb));
            float d = a - bb;
            lsum += d * d;
        }
    }
    for (int off = 32; off > 0; off >>= 1) lsum += __shfl_down(lsum, off);
    __shared__ float wred[4];
    if (lane == 0) wred[w] = lsum;
    __syncthreads();
    if (threadIdx.x == 0) atomicAdd(ma.accs + z, wred[0] + wred[1] + wred[2] + wred[3]);
}

// ---------------- finalize sims ----------------
__global__ void fin_kernel(const float* __restrict__ accs, float* __restrict__ outp) {
    if (threadIdx.x == 0) {
        float inv = 1.f / 2293760.f;
        outp[0] = accs[0] * inv;
        outp[1] = accs[1] * inv;
        outp[2] = accs[2] * inv;
        outp[3] = accs[3] * inv;
    }
}

extern "C" void kernel_launch(void* const* d_in, const int* in_sizes, int n_in,
                              void* d_out, int out_size, void* d_ws, size_t ws_size,
                              hipStream_t stream) {
    const float* const* in = (const float* const*)d_in;
    float* out = (float*)d_out;
    char* ws = (char*)d_ws;

    size_t off = 0;
    auto alloc = [&](size_t bytes) { size_t o = off; off += (bytes + 255) & ~(size_t)255; return o; };
    float*  A12   = (float*)(ws + alloc(12*N_*N_*4));
    float*  A12sq = (float*)(ws + alloc(12*N_*N_*4));
    __bf16* WcT   = (__bf16*)(ws + alloc((size_t)12*256*128*2));
    __bf16* WT    = (__bf16*)(ws + alloc((size_t)21*256*512*2));
    float*  accs  = (float*)(ws + alloc(256));
    __bf16* gout  = (__bf16*)(ws + alloc((size_t)12*ELEMS*2));
    __bf16* com   = (__bf16*)(ws + alloc((size_t)4*ELEMS*2));
    __bf16* hbf   = (__bf16*)(ws + alloc((size_t)7*ELEMS*2));
    size_t  tail  = alloc((size_t)12*ROWS*128*2);     // xAc region
    __bf16* xAc   = (__bf16*)(ws + tail);

    XPtrs xp;
    for (int i = 0; i < 12; i++) xp.p[i] = in[i];
    HPtrs hp;
    for (int i = 0; i < 7; i++) hp.p[i] = in[15 + i];

    prep_kernel<<<29, 256, 0, stream>>>(in[12], in[13], in[14], A12, A12sq,
                                        in[27], in[26], in[28], in[29],
                                        out + 7L*ELEMS + 4, accs);
    wc_kernel<<<(12*128*256)/256, 256, 0, stream>>>(in[22], in[23], in[24], in[25], WcT);
    wt_kernel<<<dim3(4, 8, 21), 256, 0, stream>>>(in[30], in[31], in[32], WT);
    hcast_kernel<<<dim3(2240, 7), 256, 0, stream>>>(hp, hbf);
    xa_kernel<<<dim3(12, 128), 256, 0, stream>>>(xp, A12, A12sq, xAc);

    // GCN: gout[r] = relu(xA1@W1) + relu(xA2@W2)  (ACT=4 split-relu at K/2=64)
    {
        GB gb{};
        for (int z = 0; z < 12; z++) { gb.a0[z] = xAc + (long)z*ROWS*128; gb.a1[z] = gb.a0[z]; }
        gemm_bf16<4><<<dim3(2, 70, 12), 256, 0, stream>>>(
            gb, 128, 128, 128, 128,
            WcT, WcT, 256, 128, 32768L,
            gout, 256, ELEMS, (const __bf16*)nullptr, 0L);
    }

    // msh + sim + com (4 batched in z)
    {
        MshA ma{};
        ma.oa[0] = gout + 3L*ELEMS; ma.ob[0] = gout + 4L*ELEMS; ma.oc[0] = ma.oa[0];
        ma.oa[1] = gout + 5L*ELEMS; ma.ob[1] = gout + 6L*ELEMS; ma.oc[1] = ma.oa[1];
        ma.oa[2] = gout + 7L*ELEMS; ma.ob[2] = gout + 8L*ELEMS; ma.oc[2] = ma.oa[2];
        ma.oa[3] = gout + 9L*ELEMS; ma.ob[3] = gout + 10L*ELEMS; ma.oc[3] = gout + 11L*ELEMS;
        ma.S[0] = in[26]; ma.S[1] = in[27]; ma.S[2] = in[28]; ma.S[3] = in[29];
        ma.com = com; ma.accs = accs;
        msh_kernel<<<dim3(256, 4, 4), 256, 0, stream>>>(ma);
    }

    fin_kernel<<<1, 64, 0, stream>>>(accs, out + 7L*ELEMS);

    // Fused GRU: gates + rh/z + final + epilogue in one kernel (no rhz round-trip)
    {
        GB gb{};
        for (int g = 0; g < 7; g++) {
            gb.a0[g] = (g < 3) ? gout + (long)g*ELEMS : com + (long)(g - 3)*ELEMS;
            gb.a1[g] = hbf + (long)g*ELEMS;
            gb.hp[g] = in[15 + g];
        }
        gru_fused<<<dim3(280, 7), 256, 0, stream>>>(gb, WT, out);
    }
}